// Round 10
// baseline (500.337 us; speedup 1.0000x reference)
//
#include <hip/hip_runtime.h>
#include <math.h>

#define NPAR 8
#define DIM  16
#define HID  128
#define BATCH 4096
#define VSTR 132               // padded stride (doubles) for 128-vectors in LDS
#define NVEC 9                 // base + 8 tangent directions

// Packed f32 weights (exact copies of f32 inputs) in static device memory.
// Layout (float offsets): PF2@0 PB2@16384 PF3@32768 PB3@49152 PF4@65536 PB4@81920 PB1@98304
// pos(jo,kr) = (((kr>>6)*16 + ((kr&63)>>2))*4 + (jo>>5))*128 + (jo&31)*4 + (kr&3)
__device__ float g_wsf[6*HID*HID + HID*DIM];

__device__ __forceinline__ double sigd(double z){ return 1.0/(1.0+exp(-z)); }
__device__ __forceinline__ double spd(double z){ return fmax(z,0.0)+log1p(exp(-fabs(z))); }
__device__ __forceinline__ int posf(int jo, int kr){
  return (((kr>>6)*16 + ((kr&63)>>2))*4 + (jo>>5))*128 + (jo&31)*4 + (kr&3);
}

__global__ void pack_weights(const float* __restrict__ W1, const float* __restrict__ W2,
                             const float* __restrict__ W3, const float* __restrict__ W4) {
  int t = blockIdx.x*blockDim.x + threadIdx.x;
  if (t < 3*HID*HID) {
    int m = t/(HID*HID); int r = t%(HID*HID);
    int j = r/HID, k = r%HID;
    const float* W = (m==0)?W2:((m==1)?W3:W4);
    float w = W[j*HID+k];
    float* PF = g_wsf + m*2*HID*HID;
    float* PB = PF + HID*HID;
    PF[posf(j,k)] = w;
    PB[posf(k,j)] = w;
  } else {
    int r = t - 3*HID*HID;
    if (r < HID*DIM) {
      int k = r/DIM, m2 = r%DIM;
      g_wsf[6*HID*HID + (k>>2)*(DIM*4) + m2*4 + (k&3)] = W1[k*DIM+m2];
    }
  }
}

// One chunk (C0..C0+NV-1 of the 9 vectors) of the split-K GEMV for TWO samples,
// sharing the weight loads/cvts. Reduces k-halves and stores into z arrays.
template<int C0, int NV>
__device__ __forceinline__ void gemv_chunk2(const float* __restrict__ Wbase,
    const double* __restrict__ h0, const double* __restrict__ h1, int o, int kh,
    double* zA0, double* zB0, double* zA1, double* zB1) {
  const float4* Wq = (const float4*)Wbase;
  const double* p0 = h0 + kh*64 + C0*VSTR;
  const double* p1 = h1 + kh*64 + C0*VSTR;
  double a0[4][NV], a1[4][NV];
#pragma unroll
  for (int jj=0;jj<4;++jj)
#pragma unroll
    for (int v=0;v<NV;++v){ a0[jj][v]=0.0; a1[jj][v]=0.0; }
#pragma unroll 2
  for (int q=0;q<16;++q){
    int base = ((kh*16+q)*4)*32 + o;
    float4 w0 = Wq[base], w1 = Wq[base+32], w2 = Wq[base+64], w3 = Wq[base+96];
    double w00=(double)w0.x,w01=(double)w0.y,w02=(double)w0.z,w03=(double)w0.w;
    double w10=(double)w1.x,w11=(double)w1.y,w12=(double)w1.z,w13=(double)w1.w;
    double w20=(double)w2.x,w21=(double)w2.y,w22=(double)w2.z,w23=(double)w2.w;
    double w30=(double)w3.x,w31=(double)w3.y,w32=(double)w3.z,w33=(double)w3.w;
#pragma unroll
    for (int v=0;v<NV;++v){
      const double2* q0p = (const double2*)(p0 + v*VSTR + 4*q);
      double2 x0 = q0p[0], x1 = q0p[1];
      a0[0][v] = fma(w03,x1.y, fma(w02,x1.x, fma(w01,x0.y, fma(w00,x0.x, a0[0][v]))));
      a0[1][v] = fma(w13,x1.y, fma(w12,x1.x, fma(w11,x0.y, fma(w10,x0.x, a0[1][v]))));
      a0[2][v] = fma(w23,x1.y, fma(w22,x1.x, fma(w21,x0.y, fma(w20,x0.x, a0[2][v]))));
      a0[3][v] = fma(w33,x1.y, fma(w32,x1.x, fma(w31,x0.y, fma(w30,x0.x, a0[3][v]))));
      const double2* q1p = (const double2*)(p1 + v*VSTR + 4*q);
      double2 y0 = q1p[0], y1 = q1p[1];
      a1[0][v] = fma(w03,y1.y, fma(w02,y1.x, fma(w01,y0.y, fma(w00,y0.x, a1[0][v]))));
      a1[1][v] = fma(w13,y1.y, fma(w12,y1.x, fma(w11,y0.y, fma(w10,y0.x, a1[1][v]))));
      a1[2][v] = fma(w23,y1.y, fma(w22,y1.x, fma(w21,y0.y, fma(w20,y0.x, a1[2][v]))));
      a1[3][v] = fma(w33,y1.y, fma(w32,y1.x, fma(w31,y0.y, fma(w30,y0.x, a1[3][v]))));
    }
  }
#pragma unroll
  for (int v=0;v<NV;++v){
    double u0 = a0[0][v] + __shfl_xor(a0[0][v],32);
    double u1 = a0[1][v] + __shfl_xor(a0[1][v],32);
    double u2 = a0[2][v] + __shfl_xor(a0[2][v],32);
    double u3 = a0[3][v] + __shfl_xor(a0[3][v],32);
    zA0[C0+v] = kh ? u2 : u0;
    zB0[C0+v] = kh ? u3 : u1;
    double s0 = a1[0][v] + __shfl_xor(a1[0][v],32);
    double s1 = a1[1][v] + __shfl_xor(a1[1][v],32);
    double s2 = a1[2][v] + __shfl_xor(a1[2][v],32);
    double s3 = a1[3][v] + __shfl_xor(a1[3][v],32);
    zA1[C0+v] = kh ? s2 : s0;
    zB1[C0+v] = kh ? s3 : s1;
  }
}

__device__ __forceinline__ void gemv9x2(const float* __restrict__ Wbase,
    const double* h0, const double* h1, int o, int kh,
    double* zA0, double* zB0, double* zA1, double* zB1) {
  gemv_chunk2<0,3>(Wbase, h0, h1, o, kh, zA0, zB0, zA1, zB1);
  gemv_chunk2<3,3>(Wbase, h0, h1, o, kh, zA0, zB0, zA1, zB1);
  gemv_chunk2<6,3>(Wbase, h0, h1, o, kh, zA0, zB0, zA1, zB1);
}

__global__ __launch_bounds__(64)
__attribute__((amdgpu_waves_per_eu(2, 2)))
void lnn_main(const float* __restrict__ x, const float* __restrict__ W1,
              const float* __restrict__ b1, const float* __restrict__ b2,
              const float* __restrict__ b3, const float* __restrict__ b4,
              const float* __restrict__ W5, float* __restrict__ out) {
  const int l  = threadIdx.x;
  const int o  = l & 31;
  const int kh = l >> 5;
  const int ja = o + 64*kh;
  const int jb = ja + 32;
  const int s0 = blockIdx.x*2;
  const int s1 = s0 + 1;

  __shared__ __align__(16) double buf0[NVEC*VSTR];
  __shared__ __align__(16) double buf1[NVEC*VSTR];
  __shared__ double xs0[16], xs1[16];

  if (l < DIM) xs0[l] = (double)x[s0*DIM + l];
  else if (l < 2*DIM) xs1[l-DIM] = (double)x[s1*DIM + (l-DIM)];
  __syncthreads();

  // ---- Phase 1: layer 1 (W1 rows ja/jb loaded once, both samples) ----
  const float4* W1v = (const float4*)W1;
  float w1af[8], w1bf[8];
  float s1a0f, s1b0f, s1a1f, s1b1f;
  {
    float4 a0 = W1v[ja*4+0], a1 = W1v[ja*4+1], a2 = W1v[ja*4+2], a3 = W1v[ja*4+3];
    float4 c0 = W1v[jb*4+0], c1 = W1v[jb*4+1], c2 = W1v[jb*4+2], c3 = W1v[jb*4+3];
    double ba = (double)b1[ja], bb = (double)b1[jb];
    double wa[16] = {(double)a0.x,(double)a0.y,(double)a0.z,(double)a0.w,
                     (double)a1.x,(double)a1.y,(double)a1.z,(double)a1.w,
                     (double)a2.x,(double)a2.y,(double)a2.z,(double)a2.w,
                     (double)a3.x,(double)a3.y,(double)a3.z,(double)a3.w};
    double wb[16] = {(double)c0.x,(double)c0.y,(double)c0.z,(double)c0.w,
                     (double)c1.x,(double)c1.y,(double)c1.z,(double)c1.w,
                     (double)c2.x,(double)c2.y,(double)c2.z,(double)c2.w,
                     (double)c3.x,(double)c3.y,(double)c3.z,(double)c3.w};
    double z1a0=ba, z1b0=bb, z1a1=ba, z1b1=bb;
#pragma unroll
    for (int k2=0;k2<16;++k2){
      z1a0 = fma(wa[k2], xs0[k2], z1a0);
      z1b0 = fma(wb[k2], xs0[k2], z1b0);
      z1a1 = fma(wa[k2], xs1[k2], z1a1);
      z1b1 = fma(wb[k2], xs1[k2], z1b1);
    }
    double sa0 = sigd(z1a0), sb0 = sigd(z1b0), sa1 = sigd(z1a1), sb1 = sigd(z1b1);
    s1a0f=(float)sa0; s1b0f=(float)sb0; s1a1f=(float)sa1; s1b1f=(float)sb1;
    buf0[ja] = spd(z1a0); buf0[jb] = spd(z1b0);
    buf1[ja] = spd(z1a1); buf1[jb] = spd(z1b1);
#pragma unroll
    for (int i=0;i<8;++i){
      w1af[i] = ((const float*)wa)[0]; // placeholder overwritten below
    }
    w1af[0]=a2.x; w1af[1]=a2.y; w1af[2]=a2.z; w1af[3]=a2.w;
    w1af[4]=a3.x; w1af[5]=a3.y; w1af[6]=a3.z; w1af[7]=a3.w;
    w1bf[0]=c2.x; w1bf[1]=c2.y; w1bf[2]=c2.z; w1bf[3]=c2.w;
    w1bf[4]=c3.x; w1bf[5]=c3.y; w1bf[6]=c3.z; w1bf[7]=c3.w;
#pragma unroll
    for (int i=0;i<8;++i){
      buf0[(1+i)*VSTR + ja] = sa0*(double)w1af[i];
      buf0[(1+i)*VSTR + jb] = sb0*(double)w1bf[i];
      buf1[(1+i)*VSTR + ja] = sa1*(double)w1af[i];
      buf1[(1+i)*VSTR + jb] = sb1*(double)w1bf[i];
    }
  }
  __syncthreads();

  double zA0[NVEC], zB0[NVEC], zA1[NVEC], zB1[NVEC];

  // ---- Phase 2: layer 2 forward (PF2) ----
  gemv9x2(g_wsf + 0, buf0, buf1, o, kh, zA0, zB0, zA1, zB1);
  float t2a0[8], t2b0[8], t2a1[8], t2b1[8];
  float s2a0f, s2b0f, s2a1f, s2b1f;
  {
    double ba = (double)b2[ja], bb = (double)b2[jb];
    double z0a = zA0[0]+ba, z0b = zB0[0]+bb, z1a = zA1[0]+ba, z1b = zB1[0]+bb;
#pragma unroll
    for (int i=0;i<8;++i){ t2a0[i]=(float)zA0[1+i]; t2b0[i]=(float)zB0[1+i];
                           t2a1[i]=(float)zA1[1+i]; t2b1[i]=(float)zB1[1+i]; }
    double sa0 = sigd(z0a), sb0 = sigd(z0b), sa1 = sigd(z1a), sb1 = sigd(z1b);
    s2a0f=(float)sa0; s2b0f=(float)sb0; s2a1f=(float)sa1; s2b1f=(float)sb1;
    __syncthreads();
    buf0[ja]=spd(z0a); buf0[jb]=spd(z0b); buf1[ja]=spd(z1a); buf1[jb]=spd(z1b);
#pragma unroll
    for (int i=0;i<8;++i){
      buf0[(1+i)*VSTR + ja] = sa0*zA0[1+i];
      buf0[(1+i)*VSTR + jb] = sb0*zB0[1+i];
      buf1[(1+i)*VSTR + ja] = sa1*zA1[1+i];
      buf1[(1+i)*VSTR + jb] = sb1*zB1[1+i];
    }
  }
  __syncthreads();

  // ---- Phase 3: layer 3 forward (PF3) ----
  gemv9x2(g_wsf + 32768, buf0, buf1, o, kh, zA0, zB0, zA1, zB1);
  float t3a0[8], t3b0[8], t3a1[8], t3b1[8];
  float s3a0f, s3b0f, s3a1f, s3b1f;
  {
    double ba = (double)b3[ja], bb = (double)b3[jb];
    double z0a = zA0[0]+ba, z0b = zB0[0]+bb, z1a = zA1[0]+ba, z1b = zB1[0]+bb;
#pragma unroll
    for (int i=0;i<8;++i){ t3a0[i]=(float)zA0[1+i]; t3b0[i]=(float)zB0[1+i];
                           t3a1[i]=(float)zA1[1+i]; t3b1[i]=(float)zB1[1+i]; }
    double sa0 = sigd(z0a), sb0 = sigd(z0b), sa1 = sigd(z1a), sb1 = sigd(z1b);
    s3a0f=(float)sa0; s3b0f=(float)sb0; s3a1f=(float)sa1; s3b1f=(float)sb1;
    __syncthreads();
    buf0[ja]=spd(z0a); buf0[jb]=spd(z0b); buf1[ja]=spd(z1a); buf1[jb]=spd(z1b);
#pragma unroll
    for (int i=0;i<8;++i){
      buf0[(1+i)*VSTR + ja] = sa0*zA0[1+i];
      buf0[(1+i)*VSTR + jb] = sb0*zB0[1+i];
      buf1[(1+i)*VSTR + ja] = sa1*zA1[1+i];
      buf1[(1+i)*VSTR + jb] = sb1*zB1[1+i];
    }
  }
  __syncthreads();

  // ---- Phase 4+5: layer 4 forward (PF4) + head ----
  gemv9x2(g_wsf + 65536, buf0, buf1, o, kh, zA0, zB0, zA1, zB1);
  {
    double ba = (double)b4[ja], bb = (double)b4[jb];
    double w5a = (double)W5[ja], w5b = (double)W5[jb];
    double z0a = zA0[0]+ba, z0b = zB0[0]+bb, z1a = zA1[0]+ba, z1b = zB1[0]+bb;
    double sa0 = sigd(z0a), sb0 = sigd(z0b), sa1 = sigd(z1a), sb1 = sigd(z1b);
    __syncthreads();
    buf0[ja]=w5a*sa0; buf0[jb]=w5b*sb0; buf1[ja]=w5a*sa1; buf1[jb]=w5b*sb1;
    double ca0 = w5a*sa0*(1.0-sa0), cb0 = w5b*sb0*(1.0-sb0);
    double ca1 = w5a*sa1*(1.0-sa1), cb1 = w5b*sb1*(1.0-sb1);
#pragma unroll
    for (int i=0;i<8;++i){
      buf0[(1+i)*VSTR + ja] = ca0*zA0[1+i];
      buf0[(1+i)*VSTR + jb] = cb0*zB0[1+i];
      buf1[(1+i)*VSTR + ja] = ca1*zA1[1+i];
      buf1[(1+i)*VSTR + jb] = cb1*zB1[1+i];
    }
  }
  __syncthreads();

  // ---- Phase 6: backward through W4^T (PB4); t3 from f32 cache ----
  gemv9x2(g_wsf + 81920, buf0, buf1, o, kh, zA0, zB0, zA1, zB1);
  {
    double sa0=(double)s3a0f, sb0=(double)s3b0f, sa1=(double)s3a1f, sb1=(double)s3b1f;
    double da0 = sa0*(1.0-sa0)*zA0[0], db0 = sb0*(1.0-sb0)*zB0[0];
    double da1 = sa1*(1.0-sa1)*zA1[0], db1 = sb1*(1.0-sb1)*zB1[0];
    __syncthreads();
    buf0[ja]=zA0[0]*sa0; buf0[jb]=zB0[0]*sb0;
    buf1[ja]=zA1[0]*sa1; buf1[jb]=zB1[0]*sb1;
#pragma unroll
    for (int i=0;i<8;++i){
      buf0[(1+i)*VSTR + ja] = fma(zA0[1+i], sa0, da0*(double)t3a0[i]);
      buf0[(1+i)*VSTR + jb] = fma(zB0[1+i], sb0, db0*(double)t3b0[i]);
      buf1[(1+i)*VSTR + ja] = fma(zA1[1+i], sa1, da1*(double)t3a1[i]);
      buf1[(1+i)*VSTR + jb] = fma(zB1[1+i], sb1, db1*(double)t3b1[i]);
    }
  }
  __syncthreads();

  // ---- Phase 7: backward through W3^T (PB3); t2 from f32 cache ----
  gemv9x2(g_wsf + 49152, buf0, buf1, o, kh, zA0, zB0, zA1, zB1);
  {
    double sa0=(double)s2a0f, sb0=(double)s2b0f, sa1=(double)s2a1f, sb1=(double)s2b1f;
    double da0 = sa0*(1.0-sa0)*zA0[0], db0 = sb0*(1.0-sb0)*zB0[0];
    double da1 = sa1*(1.0-sa1)*zA1[0], db1 = sb1*(1.0-sb1)*zB1[0];
    __syncthreads();
    buf0[ja]=zA0[0]*sa0; buf0[jb]=zB0[0]*sb0;
    buf1[ja]=zA1[0]*sa1; buf1[jb]=zB1[0]*sb1;
#pragma unroll
    for (int i=0;i<8;++i){
      buf0[(1+i)*VSTR + ja] = fma(zA0[1+i], sa0, da0*(double)t2a0[i]);
      buf0[(1+i)*VSTR + jb] = fma(zB0[1+i], sb0, db0*(double)t2b0[i]);
      buf1[(1+i)*VSTR + ja] = fma(zA1[1+i], sa1, da1*(double)t2a1[i]);
      buf1[(1+i)*VSTR + jb] = fma(zB1[1+i], sb1, db1*(double)t2b1[i]);
    }
  }
  __syncthreads();

  // ---- Phase 8: backward through W2^T (PB2); W1 tangent cols from phase-1 regs ----
  gemv9x2(g_wsf + 16384, buf0, buf1, o, kh, zA0, zB0, zA1, zB1);
  {
    double sa0=(double)s1a0f, sb0=(double)s1b0f, sa1=(double)s1a1f, sb1=(double)s1b1f;
    double da0 = sa0*(1.0-sa0)*zA0[0], db0 = sb0*(1.0-sb0)*zB0[0];
    double da1 = sa1*(1.0-sa1)*zA1[0], db1 = sb1*(1.0-sb1)*zB1[0];
    __syncthreads();
    buf0[ja]=zA0[0]*sa0; buf0[jb]=zB0[0]*sb0;
    buf1[ja]=zA1[0]*sa1; buf1[jb]=zB1[0]*sb1;
#pragma unroll
    for (int i=0;i<8;++i){
      buf0[(1+i)*VSTR + ja] = fma(zA0[1+i], sa0, da0*(double)w1af[i]);
      buf0[(1+i)*VSTR + jb] = fma(zB0[1+i], sb0, db0*(double)w1bf[i]);
      buf1[(1+i)*VSTR + ja] = fma(zA1[1+i], sa1, da1*(double)w1af[i]);
      buf1[(1+i)*VSTR + jb] = fma(zB1[1+i], sb1, db1*(double)w1bf[i]);
    }
  }
  __syncthreads();

  // ---- Phase 9: H rows (8..15) + J via W1^T (PB1), both samples ----
  double hA0=0.0, hB0=0.0, hJ0=0.0, hA1=0.0, hB1=0.0, hJ1=0.0;
  {
    const int m = l & 15, d = l >> 4;
    const float4* P1 = (const float4*)(g_wsf + 98304);
#pragma unroll 2
    for (int q=0; q<32; ++q){
      float4 wq = P1[q*DIM + m];
      double w0=(double)wq.x, w1=(double)wq.y, w2=(double)wq.z, w3=(double)wq.w;
      const double2* u0p = (const double2*)(buf0 + (1+d)*VSTR + 4*q);
      const double2* u1p = (const double2*)(buf0 + (5+d)*VSTR + 4*q);
      const double2* ggp = (const double2*)(buf0 + 4*q);
      double2 u00=u0p[0], u01=u0p[1], u10=u1p[0], u11=u1p[1], g0=ggp[0], g1=ggp[1];
      hA0 = fma(w3,u01.y, fma(w2,u01.x, fma(w1,u00.y, fma(w0,u00.x, hA0))));
      hB0 = fma(w3,u11.y, fma(w2,u11.x, fma(w1,u10.y, fma(w0,u10.x, hB0))));
      hJ0 = fma(w3,g1.y,  fma(w2,g1.x,  fma(w1,g0.y,  fma(w0,g0.x,  hJ0))));
      const double2* v0p = (const double2*)(buf1 + (1+d)*VSTR + 4*q);
      const double2* v1p = (const double2*)(buf1 + (5+d)*VSTR + 4*q);
      const double2* hgp = (const double2*)(buf1 + 4*q);
      double2 v00=v0p[0], v01=v0p[1], v10=v1p[0], v11=v1p[1], e0=hgp[0], e1=hgp[1];
      hA1 = fma(w3,v01.y, fma(w2,v01.x, fma(w1,v00.y, fma(w0,v00.x, hA1))));
      hB1 = fma(w3,v11.y, fma(w2,v11.x, fma(w1,v10.y, fma(w0,v10.x, hB1))));
      hJ1 = fma(w3,e1.y,  fma(w2,e1.x,  fma(w1,e0.y,  fma(w0,e0.x,  hJ1))));
    }
  }

  // ---- Phase 10: two pinv solves, interleaved ----
  {
    const int r = l >> 3, c = l & 7;
    double Am0, Vm0, rhs0, Am1, Vm1, rhs1;
    {
      double q0 = __shfl(hA0, ((r&3)*16) + 8 + c), q1 = __shfl(hB0, ((r&3)*16) + 8 + c);
      double Bv0 = (r < 4) ? q0 : q1;
      double c0v = __shfl(hA0, ((r&3)*16) + c),   c1v = __shfl(hB0, ((r&3)*16) + c);
      double Cr0 = (r < 4) ? c0v : c1v;
      double Jr0 = __shfl(hJ0, r);
      double p0 = Cr0 * xs0[8 + c];
      p0 += __shfl_xor(p0, 1); p0 += __shfl_xor(p0, 2); p0 += __shfl_xor(p0, 4);
      rhs0 = Jr0 - p0;
      double Bt0 = __shfl(Bv0, c*8 + r);
      Am0 = 0.5*(Bv0 + Bt0);
      Vm0 = (r == c) ? 1.0 : 0.0;

      double r0 = __shfl(hA1, ((r&3)*16) + 8 + c), r1 = __shfl(hB1, ((r&3)*16) + 8 + c);
      double Bv1 = (r < 4) ? r0 : r1;
      double d0v = __shfl(hA1, ((r&3)*16) + c),   d1v = __shfl(hB1, ((r&3)*16) + c);
      double Cr1 = (r < 4) ? d0v : d1v;
      double Jr1 = __shfl(hJ1, r);
      double p1 = Cr1 * xs1[8 + c];
      p1 += __shfl_xor(p1, 1); p1 += __shfl_xor(p1, 2); p1 += __shfl_xor(p1, 4);
      rhs1 = Jr1 - p1;
      double Bt1 = __shfl(Bv1, c*8 + r);
      Am1 = 0.5*(Bv1 + Bt1);
      Vm1 = (r == c) ? 1.0 : 0.0;
    }

    for (int sweep = 0; sweep < 6; ++sweep) {
#pragma unroll
      for (int rr = 0; rr < 7; ++rr) {
        int pc = (c == 7) ? rr : ((c == rr) ? 7 : (2*rr + 7 - c) % 7);
        int cp = min(c, pc), cq = max(c, pc);
        int pr2 = (r == 7) ? rr : ((r == rr) ? 7 : (2*rr + 7 - r) % 7);
        int rp = min(r, pr2), rq = max(r, pr2);
        // sample 0 rotation params
        double App0 = __shfl(Am0, cp*8+cp), Aqq0 = __shfl(Am0, cq*8+cq), Apq0 = __shfl(Am0, cp*8+cq);
        double tau0 = (Aqq0 - App0) / (2.0*Apq0);
        double tt0  = (tau0 >= 0.0 ? 1.0 : -1.0) / (fabs(tau0) + sqrt(1.0 + tau0*tau0));
        double cth0 = 1.0 / sqrt(1.0 + tt0*tt0);
        double sth0 = tt0 * cth0;
        if (fabs(Apq0) < 1e-300) { cth0 = 1.0; sth0 = 0.0; }
        // sample 1 rotation params
        double App1 = __shfl(Am1, cp*8+cp), Aqq1 = __shfl(Am1, cq*8+cq), Apq1 = __shfl(Am1, cp*8+cq);
        double tau1 = (Aqq1 - App1) / (2.0*Apq1);
        double tt1  = (tau1 >= 0.0 ? 1.0 : -1.0) / (fabs(tau1) + sqrt(1.0 + tau1*tau1));
        double cth1 = 1.0 / sqrt(1.0 + tt1*tt1);
        double sth1 = tt1 * cth1;
        if (fabs(Apq1) < 1e-300) { cth1 = 1.0; sth1 = 0.0; }

        double cthr0 = __shfl(cth0, r*8+r), sthr0 = __shfl(sth0, r*8+r);
        double cthr1 = __shfl(cth1, r*8+r), sthr1 = __shfl(sth1, r*8+r);

        double Arp0 = __shfl(Am0, r*8+cp), Arq0 = __shfl(Am0, r*8+cq);
        double colv0 = (c == cp) ? (cth0*Arp0 - sth0*Arq0) : (sth0*Arp0 + cth0*Arq0);
        double Arp1 = __shfl(Am1, r*8+cp), Arq1 = __shfl(Am1, r*8+cq);
        double colv1 = (c == cp) ? (cth1*Arp1 - sth1*Arq1) : (sth1*Arp1 + cth1*Arq1);

        double Mpc0 = __shfl(colv0, rp*8+c), Mqc0 = __shfl(colv0, rq*8+c);
        Am0 = (r == rp) ? (cthr0*Mpc0 - sthr0*Mqc0) : (sthr0*Mpc0 + cthr0*Mqc0);
        double Mpc1 = __shfl(colv1, rp*8+c), Mqc1 = __shfl(colv1, rq*8+c);
        Am1 = (r == rp) ? (cthr1*Mpc1 - sthr1*Mqc1) : (sthr1*Mpc1 + cthr1*Mqc1);

        double Vrp0 = __shfl(Vm0, r*8+cp), Vrq0 = __shfl(Vm0, r*8+cq);
        Vm0 = (c == cp) ? (cth0*Vrp0 - sth0*Vrq0) : (sth0*Vrp0 + cth0*Vrq0);
        double Vrp1 = __shfl(Vm1, r*8+cp), Vrq1 = __shfl(Vm1, r*8+cq);
        Vm1 = (c == cp) ? (cth1*Vrp1 - sth1*Vrq1) : (sth1*Vrp1 + cth1*Vrq1);
      }
    }

    // eigen cutoff + apply pinv, sample 0
    {
      double lam = __shfl(Am0, c*8 + c);
      double ad = (r == c) ? fabs(Am0) : 0.0;
#pragma unroll
      for (int off = 32; off; off >>= 1) ad = fmax(ad, __shfl_xor(ad, off));
      double cutoff = 9.5367431640625e-06 * ad;
      double pr = Vm0 * rhs0;
      pr += __shfl_xor(pr, 8); pr += __shfl_xor(pr, 16); pr += __shfl_xor(pr, 32);
      double w = (fabs(lam) > cutoff) ? (pr / lam) : 0.0;
      double yr = Vm0 * w;
      yr += __shfl_xor(yr, 1); yr += __shfl_xor(yr, 2); yr += __shfl_xor(yr, 4);
      if (c == 0) out[s0*NPAR + r] = (float)yr;
    }
    // sample 1
    {
      double lam = __shfl(Am1, c*8 + c);
      double ad = (r == c) ? fabs(Am1) : 0.0;
#pragma unroll
      for (int off = 32; off; off >>= 1) ad = fmax(ad, __shfl_xor(ad, off));
      double cutoff = 9.5367431640625e-06 * ad;
      double pr = Vm1 * rhs1;
      pr += __shfl_xor(pr, 8); pr += __shfl_xor(pr, 16); pr += __shfl_xor(pr, 32);
      double w = (fabs(lam) > cutoff) ? (pr / lam) : 0.0;
      double yr = Vm1 * w;
      yr += __shfl_xor(yr, 1); yr += __shfl_xor(yr, 2); yr += __shfl_xor(yr, 4);
      if (c == 0) out[s1*NPAR + r] = (float)yr;
    }
  }
}

extern "C" void kernel_launch(void* const* d_in, const int* in_sizes, int n_in,
                              void* d_out, int out_size, void* d_ws, size_t ws_size,
                              hipStream_t stream) {
  (void)in_sizes; (void)n_in; (void)out_size; (void)d_ws; (void)ws_size;
  const float* x  = (const float*)d_in[0];
  const float* W1 = (const float*)d_in[1];
  const float* b1 = (const float*)d_in[2];
  const float* W2 = (const float*)d_in[3];
  const float* b2 = (const float*)d_in[4];
  const float* W3 = (const float*)d_in[5];
  const float* b3 = (const float*)d_in[6];
  const float* W4 = (const float*)d_in[7];
  const float* b4 = (const float*)d_in[8];
  const float* W5 = (const float*)d_in[9];
  float* out = (float*)d_out;

  pack_weights<<<200, 256, 0, stream>>>(W1, W2, W3, W4);
  lnn_main<<<BATCH/2, 64, 0, stream>>>(x, W1, b1, b2, b3, b4, W5, out);
}

// Round 11
// 261.787 us; speedup vs baseline: 1.9112x; 1.9112x over previous
//
#include <hip/hip_runtime.h>
#include <math.h>

#define NPAR 8
#define DIM  16
#define HID  128
#define BATCH 4096
#define VSTRD 132              // stride (doubles) for the base vector in LDS
#define VSTRF 132              // stride (floats) per tangent vector in LDS

// Packed f32 weights (exact copies of f32 inputs) in static device memory.
// Layout (float offsets): PF2@0 PB2@16384 PF3@32768 PB3@49152 PF4@65536 PB4@81920 PB1@98304
// pos(jo,kr) = (((kr>>6)*16 + ((kr&63)>>2))*4 + (jo>>5))*128 + (jo&31)*4 + (kr&3)
__device__ float g_wsf[6*HID*HID + HID*DIM];

__device__ __forceinline__ double sigd(double z){ return 1.0/(1.0+exp(-z)); }
__device__ __forceinline__ double spd(double z){ return fmax(z,0.0)+log1p(exp(-fabs(z))); }
__device__ __forceinline__ int posf(int jo, int kr){
  return (((kr>>6)*16 + ((kr&63)>>2))*4 + (jo>>5))*128 + (jo&31)*4 + (kr&3);
}

__global__ void pack_weights(const float* __restrict__ W1, const float* __restrict__ W2,
                             const float* __restrict__ W3, const float* __restrict__ W4) {
  int t = blockIdx.x*blockDim.x + threadIdx.x;
  if (t < 3*HID*HID) {
    int m = t/(HID*HID); int r = t%(HID*HID);
    int j = r/HID, k = r%HID;
    const float* W = (m==0)?W2:((m==1)?W3:W4);
    float w = W[j*HID+k];
    float* PF = g_wsf + m*2*HID*HID;
    float* PB = PF + HID*HID;
    PF[posf(j,k)] = w;
    PB[posf(k,j)] = w;
  } else {
    int r = t - 3*HID*HID;
    if (r < HID*DIM) {
      int k = r/DIM, m2 = r%DIM;
      g_wsf[6*HID*HID + (k>>2)*(DIM*4) + m2*4 + (k&3)] = W1[k*DIM+m2];
    }
  }
}

// Mixed-precision split-K fused GEMV: base vector (f64) + 8 tangents (f32).
// Lane (o,kh) covers k-half kh, outputs {o,o+32,o+64,o+96}; after the k-half
// shfl reduction, the lane keeps outputs j_a=o+64kh, j_b=j_a+32.
__device__ __forceinline__ void gemv_mixed(const float* __restrict__ Wbase,
    const double* __restrict__ bD, const float* __restrict__ bF, int o, int kh,
    double* zDA, double* zDB, float* zFA, float* zFB) {
  const float4* Wq = (const float4*)Wbase;
  const double* pD = bD + kh*64;
  const float*  pF = bF + kh*64;
  double ad[4]; float af[4][8];
#pragma unroll
  for (int jj=0;jj<4;++jj){ ad[jj]=0.0;
#pragma unroll
    for (int v=0;v<8;++v) af[jj][v]=0.0f; }
#pragma unroll 2
  for (int q=0;q<16;++q){
    int base = ((kh*16+q)*4)*32 + o;
    float4 w0 = Wq[base], w1 = Wq[base+32], w2 = Wq[base+64], w3 = Wq[base+96];
    // base (f64): cvt weights on use
    const double2* hp = (const double2*)(pD + 4*q);
    double2 h0 = hp[0], h1 = hp[1];
    ad[0] = fma((double)w0.w,h1.y, fma((double)w0.z,h1.x, fma((double)w0.y,h0.y, fma((double)w0.x,h0.x, ad[0]))));
    ad[1] = fma((double)w1.w,h1.y, fma((double)w1.z,h1.x, fma((double)w1.y,h0.y, fma((double)w1.x,h0.x, ad[1]))));
    ad[2] = fma((double)w2.w,h1.y, fma((double)w2.z,h1.x, fma((double)w2.y,h0.y, fma((double)w2.x,h0.x, ad[2]))));
    ad[3] = fma((double)w3.w,h1.y, fma((double)w3.z,h1.x, fma((double)w3.y,h0.y, fma((double)w3.x,h0.x, ad[3]))));
    // tangents (f32)
#pragma unroll
    for (int v=0;v<8;++v){
      float4 hf = *((const float4*)(pF + v*VSTRF + 4*q));
      af[0][v] = fmaf(w0.w,hf.w, fmaf(w0.z,hf.z, fmaf(w0.y,hf.y, fmaf(w0.x,hf.x, af[0][v]))));
      af[1][v] = fmaf(w1.w,hf.w, fmaf(w1.z,hf.z, fmaf(w1.y,hf.y, fmaf(w1.x,hf.x, af[1][v]))));
      af[2][v] = fmaf(w2.w,hf.w, fmaf(w2.z,hf.z, fmaf(w2.y,hf.y, fmaf(w2.x,hf.x, af[2][v]))));
      af[3][v] = fmaf(w3.w,hf.w, fmaf(w3.z,hf.z, fmaf(w3.y,hf.y, fmaf(w3.x,hf.x, af[3][v]))));
    }
  }
  // k-half reductions + ownership select
  {
    double u0 = ad[0] + __shfl_xor(ad[0],32);
    double u1 = ad[1] + __shfl_xor(ad[1],32);
    double u2 = ad[2] + __shfl_xor(ad[2],32);
    double u3 = ad[3] + __shfl_xor(ad[3],32);
    *zDA = kh ? u2 : u0;
    *zDB = kh ? u3 : u1;
  }
#pragma unroll
  for (int v=0;v<8;++v){
    float u0 = af[0][v] + __shfl_xor(af[0][v],32);
    float u1 = af[1][v] + __shfl_xor(af[1][v],32);
    float u2 = af[2][v] + __shfl_xor(af[2][v],32);
    float u3 = af[3][v] + __shfl_xor(af[3][v],32);
    zFA[v] = kh ? u2 : u0;
    zFB[v] = kh ? u3 : u1;
  }
}

__global__ __launch_bounds__(64)
__attribute__((amdgpu_waves_per_eu(2, 4)))
void lnn_main(const float* __restrict__ x, const float* __restrict__ W1,
              const float* __restrict__ b1, const float* __restrict__ b2,
              const float* __restrict__ b3, const float* __restrict__ b4,
              const float* __restrict__ W5, float* __restrict__ out) {
  const int l  = threadIdx.x;
  const int o  = l & 31;
  const int kh = l >> 5;
  const int ja = o + 64*kh;
  const int jb = ja + 32;
  const int s  = blockIdx.x;           // one sample per wave

  __shared__ __align__(16) double bufD[VSTRD];    // base vector (f64)
  __shared__ __align__(16) float  bufF[8*VSTRF];  // 8 tangent vectors (f32)
  __shared__ double xs[16];

  if (l < DIM) xs[l] = (double)x[s*DIM + l];
  __syncthreads();

  // ---- Phase 1: layer 1 (rows ja, jb) ----
  const float4* W1v = (const float4*)W1;
  double z1a, z1b;
  float w1af[8], w1bf[8];
  {
    float4 a0 = W1v[ja*4+0], a1 = W1v[ja*4+1], a2 = W1v[ja*4+2], a3 = W1v[ja*4+3];
    float4 c0 = W1v[jb*4+0], c1 = W1v[jb*4+1], c2 = W1v[jb*4+2], c3 = W1v[jb*4+3];
    z1a = (double)b1[ja];  z1b = (double)b1[jb];
    z1a = fma((double)a0.x, xs[0],  z1a); z1a = fma((double)a0.y, xs[1],  z1a);
    z1a = fma((double)a0.z, xs[2],  z1a); z1a = fma((double)a0.w, xs[3],  z1a);
    z1a = fma((double)a1.x, xs[4],  z1a); z1a = fma((double)a1.y, xs[5],  z1a);
    z1a = fma((double)a1.z, xs[6],  z1a); z1a = fma((double)a1.w, xs[7],  z1a);
    z1a = fma((double)a2.x, xs[8],  z1a); z1a = fma((double)a2.y, xs[9],  z1a);
    z1a = fma((double)a2.z, xs[10], z1a); z1a = fma((double)a2.w, xs[11], z1a);
    z1a = fma((double)a3.x, xs[12], z1a); z1a = fma((double)a3.y, xs[13], z1a);
    z1a = fma((double)a3.z, xs[14], z1a); z1a = fma((double)a3.w, xs[15], z1a);
    z1b = fma((double)c0.x, xs[0],  z1b); z1b = fma((double)c0.y, xs[1],  z1b);
    z1b = fma((double)c0.z, xs[2],  z1b); z1b = fma((double)c0.w, xs[3],  z1b);
    z1b = fma((double)c1.x, xs[4],  z1b); z1b = fma((double)c1.y, xs[5],  z1b);
    z1b = fma((double)c1.z, xs[6],  z1b); z1b = fma((double)c1.w, xs[7],  z1b);
    z1b = fma((double)c2.x, xs[8],  z1b); z1b = fma((double)c2.y, xs[9],  z1b);
    z1b = fma((double)c2.z, xs[10], z1b); z1b = fma((double)c2.w, xs[11], z1b);
    z1b = fma((double)c3.x, xs[12], z1b); z1b = fma((double)c3.y, xs[13], z1b);
    z1b = fma((double)c3.z, xs[14], z1b); z1b = fma((double)c3.w, xs[15], z1b);
    float sa = (float)sigd(z1a), sb = (float)sigd(z1b);
    bufD[ja] = spd(z1a); bufD[jb] = spd(z1b);
    w1af[0]=a2.x; w1af[1]=a2.y; w1af[2]=a2.z; w1af[3]=a2.w;
    w1af[4]=a3.x; w1af[5]=a3.y; w1af[6]=a3.z; w1af[7]=a3.w;
    w1bf[0]=c2.x; w1bf[1]=c2.y; w1bf[2]=c2.z; w1bf[3]=c2.w;
    w1bf[4]=c3.x; w1bf[5]=c3.y; w1bf[6]=c3.z; w1bf[7]=c3.w;
#pragma unroll
    for (int i=0;i<8;++i){
      bufF[i*VSTRF + ja] = sa*w1af[i];     // t_h1 (f32)
      bufF[i*VSTRF + jb] = sb*w1bf[i];
    }
  }
  double s1a = sigd(z1a), s1b = sigd(z1b);
  __syncthreads();

  double zDA, zDB; float zFA[8], zFB[8];

  // ---- Phase 2: layer 2 forward (PF2) ----
  gemv_mixed(g_wsf + 0, bufD, bufF, o, kh, &zDA, &zDB, zFA, zFB);
  double z2a = zDA + (double)b2[ja], z2b = zDB + (double)b2[jb];
  float t2a[8], t2b[8];
#pragma unroll
  for (int i=0;i<8;++i){ t2a[i]=zFA[i]; t2b[i]=zFB[i]; }
  double s2a = sigd(z2a), s2b = sigd(z2b);
  {
    float saf = (float)s2a, sbf = (float)s2b;
    __syncthreads();
    bufD[ja] = spd(z2a); bufD[jb] = spd(z2b);
#pragma unroll
    for (int i=0;i<8;++i){
      bufF[i*VSTRF + ja] = saf*zFA[i];
      bufF[i*VSTRF + jb] = sbf*zFB[i];
    }
  }
  __syncthreads();

  // ---- Phase 3: layer 3 forward (PF3) ----
  gemv_mixed(g_wsf + 32768, bufD, bufF, o, kh, &zDA, &zDB, zFA, zFB);
  double z3a = zDA + (double)b3[ja], z3b = zDB + (double)b3[jb];
  float t3a[8], t3b[8];
#pragma unroll
  for (int i=0;i<8;++i){ t3a[i]=zFA[i]; t3b[i]=zFB[i]; }
  double s3a = sigd(z3a), s3b = sigd(z3b);
  {
    float saf = (float)s3a, sbf = (float)s3b;
    __syncthreads();
    bufD[ja] = spd(z3a); bufD[jb] = spd(z3b);
#pragma unroll
    for (int i=0;i<8;++i){
      bufF[i*VSTRF + ja] = saf*zFA[i];
      bufF[i*VSTRF + jb] = sbf*zFB[i];
    }
  }
  __syncthreads();

  // ---- Phase 4+5: layer 4 forward (PF4) + head ----
  gemv_mixed(g_wsf + 65536, bufD, bufF, o, kh, &zDA, &zDB, zFA, zFB);
  {
    double z4a = zDA + (double)b4[ja], z4b = zDB + (double)b4[jb];
    double w5a = (double)W5[ja], w5b = (double)W5[jb];
    double sa = sigd(z4a), sb = sigd(z4b);
    float caf = (float)(w5a*sa*(1.0-sa)), cbf = (float)(w5b*sb*(1.0-sb));
    __syncthreads();
    bufD[ja] = w5a*sa; bufD[jb] = w5b*sb;                 // g_z4 (f64)
#pragma unroll
    for (int i=0;i<8;++i){
      bufF[i*VSTRF + ja] = caf*zFA[i];                    // u_z4 (f32)
      bufF[i*VSTRF + jb] = cbf*zFB[i];
    }
  }
  __syncthreads();

  // ---- Phase 6: backward through W4^T (PB4) ----
  gemv_mixed(g_wsf + 81920, bufD, bufF, o, kh, &zDA, &zDB, zFA, zFB);
  {
    float saf = (float)s3a, sbf = (float)s3b;
    float daf = (float)(s3a*(1.0-s3a)*zDA), dbf = (float)(s3b*(1.0-s3b)*zDB);
    __syncthreads();
    bufD[ja] = zDA*s3a; bufD[jb] = zDB*s3b;               // g_z3
#pragma unroll
    for (int i=0;i<8;++i){
      bufF[i*VSTRF + ja] = fmaf(zFA[i], saf, daf*t3a[i]); // u_z3 (f32)
      bufF[i*VSTRF + jb] = fmaf(zFB[i], sbf, dbf*t3b[i]);
    }
  }
  __syncthreads();

  // ---- Phase 7: backward through W3^T (PB3) ----
  gemv_mixed(g_wsf + 49152, bufD, bufF, o, kh, &zDA, &zDB, zFA, zFB);
  {
    float saf = (float)s2a, sbf = (float)s2b;
    float daf = (float)(s2a*(1.0-s2a)*zDA), dbf = (float)(s2b*(1.0-s2b)*zDB);
    __syncthreads();
    bufD[ja] = zDA*s2a; bufD[jb] = zDB*s2b;               // g_z2
#pragma unroll
    for (int i=0;i<8;++i){
      bufF[i*VSTRF + ja] = fmaf(zFA[i], saf, daf*t2a[i]); // u_z2
      bufF[i*VSTRF + jb] = fmaf(zFB[i], sbf, dbf*t2b[i]);
    }
  }
  __syncthreads();

  // ---- Phase 8: backward through W2^T (PB2); W1 tangent cols from phase-1 regs ----
  gemv_mixed(g_wsf + 16384, bufD, bufF, o, kh, &zDA, &zDB, zFA, zFB);
  {
    float saf = (float)s1a, sbf = (float)s1b;
    float daf = (float)(s1a*(1.0-s1a)*zDA), dbf = (float)(s1b*(1.0-s1b)*zDB);
    __syncthreads();
    bufD[ja] = zDA*s1a; bufD[jb] = zDB*s1b;               // g_z1
#pragma unroll
    for (int i=0;i<8;++i){
      bufF[i*VSTRF + ja] = fmaf(zFA[i], saf, daf*w1af[i]); // u_z1
      bufF[i*VSTRF + jb] = fmaf(zFB[i], sbf, dbf*w1bf[i]);
    }
  }
  __syncthreads();

  // ---- Phase 9: H rows (8..15) f32 + J f64, via W1^T (PB1) ----
  float hA=0.0f, hB=0.0f; double hJ=0.0;
  {
    const int m = l & 15, d = l >> 4;
    const float4* P1 = (const float4*)(g_wsf + 98304);
#pragma unroll 4
    for (int q=0; q<32; ++q){
      float4 wq = P1[q*DIM + m];          // W1[4q..4q+3][m]
      float4 u0 = *((const float4*)(bufF + d*VSTRF + 4*q));       // u_z1 tangent d
      float4 u1 = *((const float4*)(bufF + (4+d)*VSTRF + 4*q));   // tangent 4+d
      hA = fmaf(wq.w,u0.w, fmaf(wq.z,u0.z, fmaf(wq.y,u0.y, fmaf(wq.x,u0.x, hA))));
      hB = fmaf(wq.w,u1.w, fmaf(wq.z,u1.z, fmaf(wq.y,u1.y, fmaf(wq.x,u1.x, hB))));
      const double2* ggp = (const double2*)(bufD + 4*q);
      double2 g0 = ggp[0], g1 = ggp[1];
      hJ = fma((double)wq.w,g1.y, fma((double)wq.z,g1.x,
           fma((double)wq.y,g0.y, fma((double)wq.x,g0.x, hJ))));
    }
    // lane (m,d): hA = H[8+d][m], hB = H[8+4+d][m], hJ = J[m]
  }

  // ---- Phase 10: y = pinv(B) @ (J[:8] - C qdot); f64 solve on f32-assembled B ----
  {
    const int r = l >> 3, c = l & 7;
    float BvA = __shfl(hA, ((r&3)*16) + 8 + c);
    float BvB = __shfl(hB, ((r&3)*16) + 8 + c);
    double Bv  = (double)((r < 4) ? BvA : BvB);   // B[r][c] = H[8+r][8+c]
    float CrA = __shfl(hA, ((r&3)*16) + c);
    float CrB = __shfl(hB, ((r&3)*16) + c);
    double Cr  = (double)((r < 4) ? CrA : CrB);   // C[r][c] = H[8+r][c]
    double Jr  = __shfl(hJ, r);                   // J[r]
    double p0 = Cr * xs[8 + c];
    p0 += __shfl_xor(p0, 1); p0 += __shfl_xor(p0, 2); p0 += __shfl_xor(p0, 4);
    double rhs = Jr - p0;

    // symmetrize
    double Bt = __shfl(Bv, c*8 + r);
    double Am = 0.5*(Bv + Bt);
    double Vm = (r == c) ? 1.0 : 0.0;

    // Parallel-order (round-robin) Jacobi: 4 disjoint pairs/step, 7 steps/sweep, 6 sweeps.
    for (int sweep = 0; sweep < 6; ++sweep) {
#pragma unroll
      for (int rr = 0; rr < 7; ++rr) {
        int pc = (c == 7) ? rr : ((c == rr) ? 7 : (2*rr + 7 - c) % 7);
        int cp = min(c, pc), cq = max(c, pc);
        double App = __shfl(Am, cp*8+cp);
        double Aqq = __shfl(Am, cq*8+cq);
        double Apq = __shfl(Am, cp*8+cq);
        double tau = (Aqq - App) / (2.0*Apq);
        double tt  = (tau >= 0.0 ? 1.0 : -1.0) / (fabs(tau) + sqrt(1.0 + tau*tau));
        double cth = 1.0 / sqrt(1.0 + tt*tt);
        double sth = tt * cth;
        if (fabs(Apq) < 1e-300) { cth = 1.0; sth = 0.0; }   // guard 0/0 -> NaN
        double cthr = __shfl(cth, r*8+r);
        double sthr = __shfl(sth, r*8+r);
        // column rotation: M = A*G
        double Arp = __shfl(Am, r*8+cp);
        double Arq = __shfl(Am, r*8+cq);
        double colv = (c == cp) ? (cth*Arp - sth*Arq) : (sth*Arp + cth*Arq);
        // row rotation: A = G^T*M
        int pr2 = (r == 7) ? rr : ((r == rr) ? 7 : (2*rr + 7 - r) % 7);
        int rp = min(r, pr2), rq = max(r, pr2);
        double Mpc = __shfl(colv, rp*8+c);
        double Mqc = __shfl(colv, rq*8+c);
        Am = (r == rp) ? (cthr*Mpc - sthr*Mqc) : (sthr*Mpc + cthr*Mqc);
        // V = V*G
        double Vrp = __shfl(Vm, r*8+cp);
        double Vrq = __shfl(Vm, r*8+cq);
        Vm = (c == cp) ? (cth*Vrp - sth*Vrq) : (sth*Vrp + cth*Vrq);
      }
    }

    // eigenvalue for this lane's column, and sigma_max = max |diag|
    double lam_c = __shfl(Am, c*8 + c);
    double adiag = (r == c) ? fabs(Am) : 0.0;
#pragma unroll
    for (int off = 32; off; off >>= 1) adiag = fmax(adiag, __shfl_xor(adiag, off));
    double cutoff = 9.5367431640625e-06 * adiag;   // 10*max(M,N)*eps_f32 * sigma_max

    // p_c = sum_r V[r][c]*rhs_r
    double pr = Vm * rhs;
    pr += __shfl_xor(pr, 8); pr += __shfl_xor(pr, 16); pr += __shfl_xor(pr, 32);
    double w = (fabs(lam_c) > cutoff) ? (pr / lam_c) : 0.0;
    // y_r = sum_c V[r][c]*w_c
    double yr = Vm * w;
    yr += __shfl_xor(yr, 1); yr += __shfl_xor(yr, 2); yr += __shfl_xor(yr, 4);
    if (c == 0) out[s*NPAR + r] = (float)yr;
  }
}

extern "C" void kernel_launch(void* const* d_in, const int* in_sizes, int n_in,
                              void* d_out, int out_size, void* d_ws, size_t ws_size,
                              hipStream_t stream) {
  (void)in_sizes; (void)n_in; (void)out_size; (void)d_ws; (void)ws_size;
  const float* x  = (const float*)d_in[0];
  const float* W1 = (const float*)d_in[1];
  const float* b1 = (const float*)d_in[2];
  const float* W2 = (const float*)d_in[3];
  const float* b2 = (const float*)d_in[4];
  const float* W3 = (const float*)d_in[5];
  const float* b3 = (const float*)d_in[6];
  const float* W4 = (const float*)d_in[7];
  const float* b4 = (const float*)d_in[8];
  const float* W5 = (const float*)d_in[9];
  float* out = (float*)d_out;

  pack_weights<<<200, 256, 0, stream>>>(W1, W2, W3, W4);
  lnn_main<<<BATCH, 64, 0, stream>>>(x, W1, b1, b2, b3, b4, W5, out);
}

// Round 12
// 243.970 us; speedup vs baseline: 2.0508x; 1.0730x over previous
//
#include <hip/hip_runtime.h>
#include <math.h>

#define NPAR 8
#define DIM  16
#define HID  128
#define BATCH 4096
#define VSTRF 132              // stride (floats) per 128-vector in LDS
#define NVEC 9                 // base + 8 tangent directions

// Packed f32 weights (exact copies of f32 inputs) in static device memory.
// Layout (float offsets): PF2@0 PB2@16384 PF3@32768 PB3@49152 PF4@65536 PB4@81920 PB1@98304
// pos(jo,kr) = (((kr>>6)*16 + ((kr&63)>>2))*4 + (jo>>5))*128 + (jo&31)*4 + (kr&3)
__device__ float g_wsf[6*HID*HID + HID*DIM];

__device__ __forceinline__ float sigf(float z){ return 1.0f/(1.0f+__expf(-z)); }
__device__ __forceinline__ float spf(float z){ return fmaxf(z,0.0f)+log1pf(__expf(-fabsf(z))); }
__device__ __forceinline__ int posf(int jo, int kr){
  return (((kr>>6)*16 + ((kr&63)>>2))*4 + (jo>>5))*128 + (jo&31)*4 + (kr&3);
}

__global__ void pack_weights(const float* __restrict__ W1, const float* __restrict__ W2,
                             const float* __restrict__ W3, const float* __restrict__ W4) {
  int t = blockIdx.x*blockDim.x + threadIdx.x;
  if (t < 3*HID*HID) {
    int m = t/(HID*HID); int r = t%(HID*HID);
    int j = r/HID, k = r%HID;
    const float* W = (m==0)?W2:((m==1)?W3:W4);
    float w = W[j*HID+k];
    float* PF = g_wsf + m*2*HID*HID;
    float* PB = PF + HID*HID;
    PF[posf(j,k)] = w;
    PB[posf(k,j)] = w;
  } else {
    int r = t - 3*HID*HID;
    if (r < HID*DIM) {
      int k = r/DIM, m2 = r%DIM;
      g_wsf[6*HID*HID + (k>>2)*(DIM*4) + m2*4 + (k&3)] = W1[k*DIM+m2];
    }
  }
}

// All-f32 split-K fused 9-vector GEMV. Lane (o,kh) covers k-half kh for outputs
// {o,o+32,o+64,o+96}; after the shfl_xor(32) reduction the lane keeps
// j_a = o+64*kh (zA) and j_b = j_a+32 (zB).
__device__ __forceinline__ void gemv9f32(const float* __restrict__ Wbase,
    const float* __restrict__ bin, int o, int kh, float* zA, float* zB) {
  const float4* Wq = (const float4*)Wbase;
  const float* hb = bin + kh*64;
  float acc[4][NVEC];
#pragma unroll
  for (int jj=0;jj<4;++jj)
#pragma unroll
    for (int v=0;v<NVEC;++v) acc[jj][v]=0.0f;
#pragma unroll 2
  for (int q=0;q<16;++q){
    int base = ((kh*16+q)*4)*32 + o;
    float4 w0 = Wq[base], w1 = Wq[base+32], w2 = Wq[base+64], w3 = Wq[base+96];
#pragma unroll
    for (int v=0;v<NVEC;++v){
      float4 h = *((const float4*)(hb + v*VSTRF + 4*q));   // LDS broadcast
      acc[0][v] = fmaf(w0.w,h.w, fmaf(w0.z,h.z, fmaf(w0.y,h.y, fmaf(w0.x,h.x, acc[0][v]))));
      acc[1][v] = fmaf(w1.w,h.w, fmaf(w1.z,h.z, fmaf(w1.y,h.y, fmaf(w1.x,h.x, acc[1][v]))));
      acc[2][v] = fmaf(w2.w,h.w, fmaf(w2.z,h.z, fmaf(w2.y,h.y, fmaf(w2.x,h.x, acc[2][v]))));
      acc[3][v] = fmaf(w3.w,h.w, fmaf(w3.z,h.z, fmaf(w3.y,h.y, fmaf(w3.x,h.x, acc[3][v]))));
    }
  }
#pragma unroll
  for (int v=0;v<NVEC;++v){
    float u0 = acc[0][v] + __shfl_xor(acc[0][v],32);
    float u1 = acc[1][v] + __shfl_xor(acc[1][v],32);
    float u2 = acc[2][v] + __shfl_xor(acc[2][v],32);
    float u3 = acc[3][v] + __shfl_xor(acc[3][v],32);
    zA[v] = kh ? u2 : u0;
    zB[v] = kh ? u3 : u1;
  }
}

__global__ __launch_bounds__(64)
__attribute__((amdgpu_waves_per_eu(2, 4)))
void lnn_main(const float* __restrict__ x, const float* __restrict__ W1,
              const float* __restrict__ b1, const float* __restrict__ b2,
              const float* __restrict__ b3, const float* __restrict__ b4,
              const float* __restrict__ W5, float* __restrict__ out) {
  const int l  = threadIdx.x;
  const int o  = l & 31;
  const int kh = l >> 5;
  const int ja = o + 64*kh;
  const int jb = ja + 32;
  const int s  = blockIdx.x;           // one sample per wave

  __shared__ __align__(16) float buf[NVEC*VSTRF];  // base @0, tangents @(1+i)
  __shared__ float xs[16];

  if (l < DIM) xs[l] = x[s*DIM + l];
  __syncthreads();

  // ---- Phase 1: layer 1 (rows ja, jb) ----
  const float4* W1v = (const float4*)W1;
  float s1a, s1b;
  float w1af[8], w1bf[8];
  {
    float4 a0 = W1v[ja*4+0], a1 = W1v[ja*4+1], a2 = W1v[ja*4+2], a3 = W1v[ja*4+3];
    float4 c0 = W1v[jb*4+0], c1 = W1v[jb*4+1], c2 = W1v[jb*4+2], c3 = W1v[jb*4+3];
    float z1a = b1[ja], z1b = b1[jb];
    z1a = fmaf(a0.x, xs[0],  z1a); z1a = fmaf(a0.y, xs[1],  z1a);
    z1a = fmaf(a0.z, xs[2],  z1a); z1a = fmaf(a0.w, xs[3],  z1a);
    z1a = fmaf(a1.x, xs[4],  z1a); z1a = fmaf(a1.y, xs[5],  z1a);
    z1a = fmaf(a1.z, xs[6],  z1a); z1a = fmaf(a1.w, xs[7],  z1a);
    z1a = fmaf(a2.x, xs[8],  z1a); z1a = fmaf(a2.y, xs[9],  z1a);
    z1a = fmaf(a2.z, xs[10], z1a); z1a = fmaf(a2.w, xs[11], z1a);
    z1a = fmaf(a3.x, xs[12], z1a); z1a = fmaf(a3.y, xs[13], z1a);
    z1a = fmaf(a3.z, xs[14], z1a); z1a = fmaf(a3.w, xs[15], z1a);
    z1b = fmaf(c0.x, xs[0],  z1b); z1b = fmaf(c0.y, xs[1],  z1b);
    z1b = fmaf(c0.z, xs[2],  z1b); z1b = fmaf(c0.w, xs[3],  z1b);
    z1b = fmaf(c1.x, xs[4],  z1b); z1b = fmaf(c1.y, xs[5],  z1b);
    z1b = fmaf(c1.z, xs[6],  z1b); z1b = fmaf(c1.w, xs[7],  z1b);
    z1b = fmaf(c2.x, xs[8],  z1b); z1b = fmaf(c2.y, xs[9],  z1b);
    z1b = fmaf(c2.z, xs[10], z1b); z1b = fmaf(c2.w, xs[11], z1b);
    z1b = fmaf(c3.x, xs[12], z1b); z1b = fmaf(c3.y, xs[13], z1b);
    z1b = fmaf(c3.z, xs[14], z1b); z1b = fmaf(c3.w, xs[15], z1b);
    s1a = sigf(z1a); s1b = sigf(z1b);
    buf[ja] = spf(z1a); buf[jb] = spf(z1b);
    w1af[0]=a2.x; w1af[1]=a2.y; w1af[2]=a2.z; w1af[3]=a2.w;
    w1af[4]=a3.x; w1af[5]=a3.y; w1af[6]=a3.z; w1af[7]=a3.w;
    w1bf[0]=c2.x; w1bf[1]=c2.y; w1bf[2]=c2.z; w1bf[3]=c2.w;
    w1bf[4]=c3.x; w1bf[5]=c3.y; w1bf[6]=c3.z; w1bf[7]=c3.w;
#pragma unroll
    for (int i=0;i<8;++i){
      buf[(1+i)*VSTRF + ja] = s1a*w1af[i];     // t_h1
      buf[(1+i)*VSTRF + jb] = s1b*w1bf[i];
    }
  }
  __syncthreads();

  float zA[NVEC], zB[NVEC];

  // ---- Phase 2: layer 2 forward (PF2) ----
  gemv9f32(g_wsf + 0, buf, o, kh, zA, zB);
  float z2a = zA[0] + b2[ja], z2b = zB[0] + b2[jb];
  float t2a[8], t2b[8];
#pragma unroll
  for (int i=0;i<8;++i){ t2a[i]=zA[1+i]; t2b[i]=zB[1+i]; }
  float s2a = sigf(z2a), s2b = sigf(z2b);
  __syncthreads();
  buf[ja] = spf(z2a); buf[jb] = spf(z2b);
#pragma unroll
  for (int i=0;i<8;++i){
    buf[(1+i)*VSTRF + ja] = s2a*zA[1+i];
    buf[(1+i)*VSTRF + jb] = s2b*zB[1+i];
  }
  __syncthreads();

  // ---- Phase 3: layer 3 forward (PF3) ----
  gemv9f32(g_wsf + 32768, buf, o, kh, zA, zB);
  float z3a = zA[0] + b3[ja], z3b = zB[0] + b3[jb];
  float t3a[8], t3b[8];
#pragma unroll
  for (int i=0;i<8;++i){ t3a[i]=zA[1+i]; t3b[i]=zB[1+i]; }
  float s3a = sigf(z3a), s3b = sigf(z3b);
  __syncthreads();
  buf[ja] = spf(z3a); buf[jb] = spf(z3b);
#pragma unroll
  for (int i=0;i<8;++i){
    buf[(1+i)*VSTRF + ja] = s3a*zA[1+i];
    buf[(1+i)*VSTRF + jb] = s3b*zB[1+i];
  }
  __syncthreads();

  // ---- Phase 4+5: layer 4 forward (PF4) + head ----
  gemv9f32(g_wsf + 65536, buf, o, kh, zA, zB);
  {
    float z4a = zA[0] + b4[ja], z4b = zB[0] + b4[jb];
    float w5a = W5[ja], w5b = W5[jb];
    float sa = sigf(z4a), sb = sigf(z4b);
    float ca = w5a*sa*(1.0f-sa), cb = w5b*sb*(1.0f-sb);
    __syncthreads();
    buf[ja] = w5a*sa; buf[jb] = w5b*sb;                   // g_z4
#pragma unroll
    for (int i=0;i<8;++i){
      buf[(1+i)*VSTRF + ja] = ca*zA[1+i];                 // u_z4
      buf[(1+i)*VSTRF + jb] = cb*zB[1+i];
    }
  }
  __syncthreads();

  // ---- Phase 6: backward through W4^T (PB4) ----
  gemv9f32(g_wsf + 81920, buf, o, kh, zA, zB);
  {
    float da = s3a*(1.0f-s3a)*zA[0], db = s3b*(1.0f-s3b)*zB[0];
    __syncthreads();
    buf[ja] = zA[0]*s3a; buf[jb] = zB[0]*s3b;             // g_z3
#pragma unroll
    for (int i=0;i<8;++i){
      buf[(1+i)*VSTRF + ja] = fmaf(zA[1+i], s3a, da*t3a[i]);  // u_z3
      buf[(1+i)*VSTRF + jb] = fmaf(zB[1+i], s3b, db*t3b[i]);
    }
  }
  __syncthreads();

  // ---- Phase 7: backward through W3^T (PB3) ----
  gemv9f32(g_wsf + 49152, buf, o, kh, zA, zB);
  {
    float da = s2a*(1.0f-s2a)*zA[0], db = s2b*(1.0f-s2b)*zB[0];
    __syncthreads();
    buf[ja] = zA[0]*s2a; buf[jb] = zB[0]*s2b;             // g_z2
#pragma unroll
    for (int i=0;i<8;++i){
      buf[(1+i)*VSTRF + ja] = fmaf(zA[1+i], s2a, da*t2a[i]);  // u_z2
      buf[(1+i)*VSTRF + jb] = fmaf(zB[1+i], s2b, db*t2b[i]);
    }
  }
  __syncthreads();

  // ---- Phase 8: backward through W2^T (PB2); W1 tangent cols from phase-1 regs ----
  gemv9f32(g_wsf + 16384, buf, o, kh, zA, zB);
  {
    float da = s1a*(1.0f-s1a)*zA[0], db = s1b*(1.0f-s1b)*zB[0];
    __syncthreads();
    buf[ja] = zA[0]*s1a; buf[jb] = zB[0]*s1b;             // g_z1
#pragma unroll
    for (int i=0;i<8;++i){
      buf[(1+i)*VSTRF + ja] = fmaf(zA[1+i], s1a, da*w1af[i]); // u_z1
      buf[(1+i)*VSTRF + jb] = fmaf(zB[1+i], s1b, db*w1bf[i]);
    }
  }
  __syncthreads();

  // ---- Phase 9: H rows (8..15) + J via W1^T (PB1), all f32 ----
  float hA=0.0f, hB=0.0f, hJ=0.0f;
  {
    const int m = l & 15, d = l >> 4;
    const float4* P1 = (const float4*)(g_wsf + 98304);
#pragma unroll 4
    for (int q=0; q<32; ++q){
      float4 wq = P1[q*DIM + m];          // W1[4q..4q+3][m]
      float4 u0 = *((const float4*)(buf + (1+d)*VSTRF + 4*q));
      float4 u1 = *((const float4*)(buf + (5+d)*VSTRF + 4*q));
      float4 gg = *((const float4*)(buf + 4*q));
      hA = fmaf(wq.w,u0.w, fmaf(wq.z,u0.z, fmaf(wq.y,u0.y, fmaf(wq.x,u0.x, hA))));
      hB = fmaf(wq.w,u1.w, fmaf(wq.z,u1.z, fmaf(wq.y,u1.y, fmaf(wq.x,u1.x, hB))));
      hJ = fmaf(wq.w,gg.w, fmaf(wq.z,gg.z, fmaf(wq.y,gg.y, fmaf(wq.x,gg.x, hJ))));
    }
    // lane (m,d): hA = H[8+d][m], hB = H[8+4+d][m], hJ = J[m]
  }

  // ---- Phase 10: y = pinv(B) @ (J[:8] - C qdot); f64 solve on f32-assembled B ----
  {
    const int r = l >> 3, c = l & 7;
    float BvA = __shfl(hA, ((r&3)*16) + 8 + c);
    float BvB = __shfl(hB, ((r&3)*16) + 8 + c);
    double Bv  = (double)((r < 4) ? BvA : BvB);   // B[r][c] = H[8+r][8+c]
    float CrA = __shfl(hA, ((r&3)*16) + c);
    float CrB = __shfl(hB, ((r&3)*16) + c);
    double Cr  = (double)((r < 4) ? CrA : CrB);   // C[r][c] = H[8+r][c]
    double Jr  = (double)__shfl(hJ, r);           // J[r]
    double p0 = Cr * (double)xs[8 + c];
    p0 += __shfl_xor(p0, 1); p0 += __shfl_xor(p0, 2); p0 += __shfl_xor(p0, 4);
    double rhs = Jr - p0;

    // symmetrize
    double Bt = __shfl(Bv, c*8 + r);
    double Am = 0.5*(Bv + Bt);
    double Vm = (r == c) ? 1.0 : 0.0;

    // Parallel-order (round-robin) Jacobi: 4 disjoint pairs/step, 7 steps/sweep, 5 sweeps.
    for (int sweep = 0; sweep < 5; ++sweep) {
#pragma unroll
      for (int rr = 0; rr < 7; ++rr) {
        int pc = (c == 7) ? rr : ((c == rr) ? 7 : (2*rr + 7 - c) % 7);
        int cp = min(c, pc), cq = max(c, pc);
        double App = __shfl(Am, cp*8+cp);
        double Aqq = __shfl(Am, cq*8+cq);
        double Apq = __shfl(Am, cp*8+cq);
        double tau = (Aqq - App) / (2.0*Apq);
        double tt  = (tau >= 0.0 ? 1.0 : -1.0) / (fabs(tau) + sqrt(1.0 + tau*tau));
        double cth = 1.0 / sqrt(1.0 + tt*tt);
        double sth = tt * cth;
        if (fabs(Apq) < 1e-300) { cth = 1.0; sth = 0.0; }   // guard 0/0 -> NaN
        double cthr = __shfl(cth, r*8+r);
        double sthr = __shfl(sth, r*8+r);
        // column rotation: M = A*G
        double Arp = __shfl(Am, r*8+cp);
        double Arq = __shfl(Am, r*8+cq);
        double colv = (c == cp) ? (cth*Arp - sth*Arq) : (sth*Arp + cth*Arq);
        // row rotation: A = G^T*M
        int pr2 = (r == 7) ? rr : ((r == rr) ? 7 : (2*rr + 7 - r) % 7);
        int rp = min(r, pr2), rq = max(r, pr2);
        double Mpc = __shfl(colv, rp*8+c);
        double Mqc = __shfl(colv, rq*8+c);
        Am = (r == rp) ? (cthr*Mpc - sthr*Mqc) : (sthr*Mpc + cthr*Mqc);
        // V = V*G
        double Vrp = __shfl(Vm, r*8+cp);
        double Vrq = __shfl(Vm, r*8+cq);
        Vm = (c == cp) ? (cth*Vrp - sth*Vrq) : (sth*Vrp + cth*Vrq);
      }
    }

    // eigenvalue for this lane's column, and sigma_max = max |diag|
    double lam_c = __shfl(Am, c*8 + c);
    double adiag = (r == c) ? fabs(Am) : 0.0;
#pragma unroll
    for (int off = 32; off; off >>= 1) adiag = fmax(adiag, __shfl_xor(adiag, off));
    double cutoff = 9.5367431640625e-06 * adiag;   // 10*max(M,N)*eps_f32 * sigma_max

    // p_c = sum_r V[r][c]*rhs_r
    double pr = Vm * rhs;
    pr += __shfl_xor(pr, 8); pr += __shfl_xor(pr, 16); pr += __shfl_xor(pr, 32);
    double w = (fabs(lam_c) > cutoff) ? (pr / lam_c) : 0.0;
    // y_r = sum_c V[r][c]*w_c
    double yr = Vm * w;
    yr += __shfl_xor(yr, 1); yr += __shfl_xor(yr, 2); yr += __shfl_xor(yr, 4);
    if (c == 0) out[s*NPAR + r] = (float)yr;
  }
}

extern "C" void kernel_launch(void* const* d_in, const int* in_sizes, int n_in,
                              void* d_out, int out_size, void* d_ws, size_t ws_size,
                              hipStream_t stream) {
  (void)in_sizes; (void)n_in; (void)out_size; (void)d_ws; (void)ws_size;
  const float* x  = (const float*)d_in[0];
  const float* W1 = (const float*)d_in[1];
  const float* b1 = (const float*)d_in[2];
  const float* W2 = (const float*)d_in[3];
  const float* b2 = (const float*)d_in[4];
  const float* W3 = (const float*)d_in[5];
  const float* b3 = (const float*)d_in[6];
  const float* W4 = (const float*)d_in[7];
  const float* b4 = (const float*)d_in[8];
  const float* W5 = (const float*)d_in[9];
  float* out = (float*)d_out;

  pack_weights<<<200, 256, 0, stream>>>(W1, W2, W3, W4);
  lnn_main<<<BATCH, 64, 0, stream>>>(x, W1, b1, b2, b3, b4, W5, out);
}